// Round 5
// baseline (990.357 us; speedup 1.0000x reference)
//
#include <hip/hip_runtime.h>

typedef unsigned short u16;
typedef unsigned int u32;
typedef __attribute__((ext_vector_type(4))) float f32x4;
typedef __attribute__((ext_vector_type(8))) short bf16x8;
typedef __attribute__((ext_vector_type(4))) short bf16x4;
typedef __attribute__((ext_vector_type(4))) u16 u16x4;

#define N_NODES 16384
#define N_EDGES 8192
#define FK_SCALE 0.17677669529663687f
#define LOG2E 1.4426950408889634f
#define C1EXP (FK_SCALE * LOG2E)
#define NSPLIT 4

typedef const u32 __attribute__((address_space(1))) gu32;
typedef u32 __attribute__((address_space(3))) lu32;

__device__ __forceinline__ void gl_lds16(const void* g, void* l) {
  __builtin_amdgcn_global_load_lds((gu32*)g, (lu32*)l, 16, 0, 0);
}

__device__ __forceinline__ float b2f(u16 u) {
  return __builtin_bit_cast(float, (u32)u << 16);
}
__device__ __forceinline__ u16 f2b(float f) {
  u32 u = __builtin_bit_cast(u32, f);
  u += 0x7fffu + ((u >> 16) & 1u);
  return (u16)(u >> 16);
}

// ---------------- X -> bf16 ----------------
__global__ __launch_bounds__(256) void k_cvt(const float* __restrict__ X,
                                             u16* __restrict__ Xb) {
  int i = blockIdx.x * 256 + threadIdx.x;
  f32x4 v = *(const f32x4*)(X + i * 4);
  u16x4 r;
  r.x = f2b(v.x); r.y = f2b(v.y); r.z = f2b(v.z); r.w = f2b(v.w);
  *(u16x4*)(Xb + i * 4) = r;
}

// ---------------- W transpose+cvt ----------------
__global__ __launch_bounds__(256) void k_wt(const float* __restrict__ Wq,
                                            const float* __restrict__ Wk,
                                            const float* __restrict__ Wv,
                                            const float* __restrict__ Wke,
                                            u16* __restrict__ Wt) {
  int w = blockIdx.y;
  const float* W = (w == 0) ? Wq : (w == 1) ? Wk : (w == 2) ? Wv : Wke;
  int n = blockIdx.x;
  int k = threadIdx.x;
  Wt[w * 65536 + n * 256 + k] = f2b(W[k * 256 + n]);
}

// ---------------- bias pack ----------------
__global__ __launch_bounds__(256) void k_bias(const float* __restrict__ bq,
                                              const float* __restrict__ bk,
                                              const float* __restrict__ bv,
                                              const float* __restrict__ bke,
                                              float* __restrict__ bcat) {
  int i = blockIdx.x * 256 + threadIdx.x;
  float v;
  if (i < 256) v = bq[i];
  else if (i < 512) v = bk[i - 256];
  else if (i < 768) v = bv[i - 512];
  else v = bke[i - 768];
  bcat[i] = v;
}

// ---------------- histogram of e_ids ----------------
__global__ __launch_bounds__(256) void k_hist(const int* __restrict__ e_ids,
                                              int* __restrict__ hist) {
  int base = blockIdx.x * 1024 + threadIdx.x;
#pragma unroll
  for (int k = 0; k < 4; k++) atomicAdd(&hist[e_ids[base + k * 256]], 1);
}

// ---------------- exclusive scan (1 block) ----------------
__global__ __launch_bounds__(256) void k_scan(const int* __restrict__ hist,
                                              int* __restrict__ eoff,
                                              int* __restrict__ cur) {
  __shared__ int ts[256];
  int t = threadIdx.x;
  int base = t * 32;
  int vals[32];
  int s = 0;
#pragma unroll
  for (int i = 0; i < 32; i++) { vals[i] = hist[base + i]; s += vals[i]; }
  ts[t] = s;
  __syncthreads();
  for (int off = 1; off < 256; off <<= 1) {
    int v = (t >= off) ? ts[t - off] : 0;
    __syncthreads();
    ts[t] += v;
    __syncthreads();
  }
  int ex = ts[t] - s;
#pragma unroll
  for (int i = 0; i < 32; i++) {
    eoff[base + i] = ex;
    cur[base + i] = ex;
    ex += vals[i];
  }
  if (t == 255) eoff[8192] = ex;
}

// ---------------- permute ----------------
__global__ __launch_bounds__(256) void k_perm(const int* __restrict__ v_ids,
                                              const int* __restrict__ e_ids,
                                              int* __restrict__ cur,
                                              int* __restrict__ perm) {
  int base = blockIdx.x * 1024 + threadIdx.x;
#pragma unroll
  for (int k = 0; k < 4; k++) {
    int i = base + k * 256;
    int e = e_ids[i];
    int v = v_ids[i];
    int pos = atomicAdd(&cur[e], 1);
    perm[pos] = v;
  }
}

// ---------------- per-edge gather-mean ----------------
__global__ __launch_bounds__(256) void k_gather(const u16* __restrict__ Xb,
                                                const int* __restrict__ perm,
                                                const int* __restrict__ eoff,
                                                u16* __restrict__ Xe) {
  __shared__ float red[4][256];
  int e = blockIdx.x;
  int tid = threadIdx.x, wave = tid >> 6, lane = tid & 63;
  int start = eoff[e], end = eoff[e + 1];
  f32x4 acc = {0.f, 0.f, 0.f, 0.f};
  for (int j = start + wave; j < end; j += 4) {
    int v = perm[j];
    bf16x4 x = *(const bf16x4*)(Xb + v * 256 + lane * 4);
#pragma unroll
    for (int c = 0; c < 4; c++) acc[c] += b2f((u16)x[c]);
  }
  *(f32x4*)&red[wave][lane * 4] = acc;
  __syncthreads();
  int t = tid;
  float s = red[0][t] + red[1][t] + red[2][t] + red[3][t];
  float m = s / fmaxf((float)(end - start), 1.0f);
  Xe[e * 256 + t] = f2b(m);
}

// ---------------- transpose Xe -> XeT ----------------
__global__ __launch_bounds__(256) void k_xt(const u16* __restrict__ Xe,
                                            u16* __restrict__ XeT) {
  __shared__ u16 tile[64][65];
  int e0 = blockIdx.x * 64, c0 = blockIdx.y * 64;
  int tid = threadIdx.x;
#pragma unroll
  for (int i = 0; i < 16; i++) {
    int idx = i * 256 + tid;
    int er = idx >> 6, cr = idx & 63;
    tile[cr][er] = Xe[(e0 + er) * 256 + c0 + cr];
  }
  __syncthreads();
#pragma unroll
  for (int i = 0; i < 16; i++) {
    int idx = i * 256 + tid;
    int cr = idx >> 6, er = idx & 63;
    XeT[(c0 + cr) * 8192 + e0 + er] = tile[cr][er];
  }
}

// ---------------- GEMM 64x64, K=256 ----------------
__global__ __launch_bounds__(256) void k_gemm64(const u16* __restrict__ A,
                                                const u16* __restrict__ Wt,
                                                const float* __restrict__ bias,
                                                u16* __restrict__ out,
                                                int ldout) {
  __shared__ u16 As[64 * 256];
  __shared__ u16 Bs[64 * 256];
  int tid = threadIdx.x;
  int mtile = blockIdx.x * 64;
  int gn = blockIdx.y * 64;
  const u16* Ap = A + mtile * 256;
  const u16* Bp = Wt + gn * 256;
#pragma unroll
  for (int i = 0; i < 8; i++) {
    gl_lds16(Ap + i * 2048 + tid * 8, As + i * 2048 + tid * 8);
    gl_lds16(Bp + i * 2048 + tid * 8, Bs + i * 2048 + tid * 8);
  }
  __syncthreads();
  int wave = tid >> 6, lane = tid & 63;
  int quad = lane >> 4, l16 = lane & 15;
  bf16x8 a[8];
#pragma unroll
  for (int kc = 0; kc < 8; kc++)
    a[kc] = *(const bf16x8*)(As + (wave * 16 + l16) * 256 + kc * 32 + quad * 8);
#pragma unroll
  for (int nt = 0; nt < 4; nt++) {
    f32x4 acc = {0.f, 0.f, 0.f, 0.f};
#pragma unroll
    for (int kc = 0; kc < 8; kc++) {
      bf16x8 b = *(const bf16x8*)(Bs + (nt * 16 + l16) * 256 + kc * 32 + quad * 8);
      acc = __builtin_amdgcn_mfma_f32_16x16x32_bf16(a[kc], b, acc, 0, 0, 0);
    }
#pragma unroll
    for (int r = 0; r < 4; r++) {
      int row = mtile + wave * 16 + quad * 4 + r;
      int col = gn + nt * 16 + l16;
      out[row * ldout + col] = f2b(acc[r] + bias[col]);
    }
  }
}

// ---------------- kappa = max_e ||Ke_e||^2 (256 atomics total) ----------------
__global__ __launch_bounds__(256) void k_knorm(const u16* __restrict__ Keb,
                                               float* __restrict__ kappa) {
  __shared__ float red[4];
  int tid = threadIdx.x;
  int wave = tid >> 6, lane = tid & 63;
  float mx = 0.f;
#pragma unroll
  for (int i = 0; i < 8; i++) {
    int e = blockIdx.x * 32 + wave * 8 + i;
    bf16x4 x = *(const bf16x4*)(Keb + e * 256 + lane * 4);
    float s = 0.f;
#pragma unroll
    for (int c = 0; c < 4; c++) { float v = b2f((u16)x[c]); s += v * v; }
#pragma unroll
    for (int off = 1; off < 64; off <<= 1) s += __shfl_xor(s, off, 64);
    mx = fmaxf(mx, s);
  }
  if (lane == 0) red[wave] = mx;
  __syncthreads();
  if (tid == 0) {
    float m = fmaxf(fmaxf(red[0], red[1]), fmaxf(red[2], red[3]));
    atomicMax((int*)kappa, __float_as_int(m));  // all values >= 0
  }
}

// ---------------- M2row[n] = ||Qe_n|| * sqrt(kappa) * scale * log2e ----------------
__global__ __launch_bounds__(256) void k_qnorm(const u16* __restrict__ QKV,
                                               const float* __restrict__ kappa,
                                               float* __restrict__ M2row) {
  int tid = threadIdx.x;
  int wave = tid >> 6, lane = tid & 63;
  int n = blockIdx.x * 4 + wave;
  bf16x4 x = *(const bf16x4*)(QKV + n * 768 + lane * 4);
  float s = 0.f;
#pragma unroll
  for (int c = 0; c < 4; c++) { float v = b2f((u16)x[c]); s += v * v; }
#pragma unroll
  for (int off = 1; off < 64; off <<= 1) s += __shfl_xor(s, off, 64);
  if (lane == 0) M2row[n] = sqrtf(s * kappa[0]) * C1EXP;
}

// ---------------- per-node 8x8 head attention ----------------
__global__ __launch_bounds__(256) void k_nodeattn(const u16* __restrict__ QKV,
                                                  float* __restrict__ Xnode) {
  int tid = threadIdx.x;
  int wave = tid >> 6, lane = tid & 63;
  int n = blockIdx.x * 4 + wave;
  int h = lane >> 3, g = lane & 7;
  const u16* base = QKV + n * 768;
  const bf16x8* qp = (const bf16x8*)(base + h * 32);
  const bf16x8* kp = (const bf16x8*)(base + 256 + g * 32);
  float s = 0.f;
#pragma unroll
  for (int t = 0; t < 4; t++) {
    bf16x8 qv = qp[t], kv = kp[t];
#pragma unroll
    for (int j = 0; j < 8; j++) s += b2f((u16)qv[j]) * b2f((u16)kv[j]);
  }
  s *= FK_SCALE;
  float mx = s;
#pragma unroll
  for (int off = 1; off < 8; off <<= 1) mx = fmaxf(mx, __shfl_xor(mx, off, 64));
  float p = __builtin_amdgcn_exp2f((s - mx) * LOG2E);
  float l = p;
#pragma unroll
  for (int off = 1; off < 8; off <<= 1) l += __shfl_xor(l, off, 64);
  float attn = p / l;
  float a4[4] = {0.f, 0.f, 0.f, 0.f};
#pragma unroll
  for (int g2 = 0; g2 < 8; g2++) {
    float a = __shfl(attn, (lane & 56) | g2, 64);
    bf16x4 vv = *(const bf16x4*)(base + 512 + g2 * 32 + g * 4);
#pragma unroll
    for (int j = 0; j < 4; j++) a4[j] += a * b2f((u16)vv[j]);
  }
  f32x4 o = {a4[0], a4[1], a4[2], a4[3]};
  *(f32x4*)(Xnode + n * 256 + h * 32 + g * 4) = o;
}

// ---------------- flash partial, STREAMING (no Ke/V LDS, no barriers) ----------------
// 512 blocks = 128 q-tiles x 4 splits; 4 waves; Bq=32/wave; Bk=64; 32 kt iters.
// Ke/V B-fragments read directly from L2-resident global. Only P uses LDS
// (per-wave 2 KB, swizzled, same-wave round trip -> no __syncthreads at all).
__global__ __launch_bounds__(256) void k_flash(const u16* __restrict__ QKV,
                                               const u16* __restrict__ Keb,
                                               const u16* __restrict__ XeT,
                                               const float* __restrict__ M2row,
                                               u16* __restrict__ Op,
                                               float* __restrict__ Lv) {
  __shared__ u16 PL[4][2048];  // per-wave [32 rows][64 cols] bf16, chunk-swizzled
  int tid = threadIdx.x;
  int wave = tid >> 6, lane = tid & 63;
  int quad = lane >> 4, l16 = lane & 15;
  int qt = blockIdx.x & 127;
  int split = blockIdx.x >> 7;
  int row0 = qt * 128 + wave * 32;
  u16* PLw = PL[wave];

  // Q fragments for 2 m-tiles
  bf16x8 qf[2][8];
#pragma unroll
  for (int mt = 0; mt < 2; mt++)
#pragma unroll
    for (int kc = 0; kc < 8; kc++)
      qf[mt][kc] = *(const bf16x8*)(QKV + (row0 + mt * 16 + l16) * 768 + kc * 32 + quad * 8);

  float mb0[4], mb1[4];
#pragma unroll
  for (int r = 0; r < 4; r++) {
    mb0[r] = M2row[row0 + quad * 4 + r];
    mb1[r] = M2row[row0 + 16 + quad * 4 + r];
  }

  f32x4 o0[16], o1[16];
#pragma unroll
  for (int i = 0; i < 16; i++) {
    o0[i] = (f32x4){0.f, 0.f, 0.f, 0.f};
    o1[i] = (f32x4){0.f, 0.f, 0.f, 0.f};
  }
  float l0[4] = {0.f, 0.f, 0.f, 0.f}, l1[4] = {0.f, 0.f, 0.f, 0.f};

  const u16* kfb = Keb + (size_t)split * 32 * 16384 + l16 * 256 + quad * 8;
  const u16* vfb = XeT + (size_t)split * 2048 + (size_t)l16 * 8192 + quad * 8;

  for (int ktl = 0; ktl < 32; ktl++) {
    const u16* kb = kfb + ktl * 16384;
    // QK^T: nt processed in pairs -> 4 independent MFMA chains
#pragma unroll
    for (int np = 0; np < 2; np++) {
      bf16x8 k0[8], k1[8];
#pragma unroll
      for (int kc = 0; kc < 8; kc++) {
        k0[kc] = *(const bf16x8*)(kb + (np * 32) * 256 + kc * 32);
        k1[kc] = *(const bf16x8*)(kb + (np * 32 + 16) * 256 + kc * 32);
      }
      f32x4 a00 = {0.f, 0.f, 0.f, 0.f}, a10 = a00, a01 = a00, a11 = a00;
#pragma unroll
      for (int kc = 0; kc < 8; kc++) {
        a00 = __builtin_amdgcn_mfma_f32_16x16x32_bf16(qf[0][kc], k0[kc], a00, 0, 0, 0);
        a10 = __builtin_amdgcn_mfma_f32_16x16x32_bf16(qf[1][kc], k0[kc], a10, 0, 0, 0);
        a01 = __builtin_amdgcn_mfma_f32_16x16x32_bf16(qf[0][kc], k1[kc], a01, 0, 0, 0);
        a11 = __builtin_amdgcn_mfma_f32_16x16x32_bf16(qf[1][kc], k1[kc], a11, 0, 0, 0);
      }
      // exp + P store for nt = 2*np (a00,a10) and nt = 2*np+1 (a01,a11)
#pragma unroll
      for (int h = 0; h < 2; h++) {
        const f32x4& b0 = (h == 0) ? a00 : a01;
        const f32x4& b1 = (h == 0) ? a10 : a11;
        int col = (np * 2 + h) * 16 + l16;
#pragma unroll
        for (int r = 0; r < 4; r++) {
          float pv = __builtin_amdgcn_exp2f(b0[r] * C1EXP - mb0[r]);
          l0[r] += pv;
          int row = quad * 4 + r;
          PLw[row * 64 + (((col >> 3) ^ (row & 7)) << 3) + (col & 7)] = f2b(pv);
          pv = __builtin_amdgcn_exp2f(b1[r] * C1EXP - mb1[r]);
          l1[r] += pv;
          row = 16 + quad * 4 + r;
          PLw[row * 64 + (((col >> 3) ^ (row & 7)) << 3) + (col & 7)] = f2b(pv);
        }
      }
    }
    // P A-fragments (same-wave LDS round trip; compiler inserts lgkmcnt)
    bf16x8 pf0[2], pf1[2];
#pragma unroll
    for (int kc2 = 0; kc2 < 2; kc2++) {
      int ck = kc2 * 4 + quad;
      int ra = l16;
      pf0[kc2] = *(const bf16x8*)(PLw + ra * 64 + ((ck ^ (ra & 7)) << 3));
      ra = 16 + l16;
      pf1[kc2] = *(const bf16x8*)(PLw + ra * 64 + ((ck ^ (ra & 7)) << 3));
    }
    // PV: V B-fragments streamed from L2; 16 independent chains per m-tile
    const u16* vb0 = vfb + ktl * 64;
#pragma unroll
    for (int ct = 0; ct < 16; ct++) {
#pragma unroll
      for (int kc2 = 0; kc2 < 2; kc2++) {
        bf16x8 vb = *(const bf16x8*)(vb0 + (size_t)ct * 131072 + kc2 * 32);
        o0[ct] = __builtin_amdgcn_mfma_f32_16x16x32_bf16(pf0[kc2], vb, o0[ct], 0, 0, 0);
        o1[ct] = __builtin_amdgcn_mfma_f32_16x16x32_bf16(pf1[kc2], vb, o1[ct], 0, 0, 0);
      }
    }
  }

  // reduce row-sums across the 16 lanes of each row
#pragma unroll
  for (int off = 1; off < 16; off <<= 1)
#pragma unroll
    for (int r = 0; r < 4; r++) {
      l0[r] += __shfl_xor(l0[r], off, 64);
      l1[r] += __shfl_xor(l1[r], off, 64);
    }

  size_t obase = (size_t)split * N_NODES * 256;
#pragma unroll
  for (int ct = 0; ct < 16; ct++)
#pragma unroll
    for (int r = 0; r < 4; r++) {
      int row = row0 + quad * 4 + r;
      int col = ct * 16 + l16;
      Op[obase + (size_t)row * 256 + col] = f2b(o0[ct][r]);
      Op[obase + (size_t)(row + 16) * 256 + col] = f2b(o1[ct][r]);
    }
  if (l16 == 0) {
#pragma unroll
    for (int r = 0; r < 4; r++) {
      int row = row0 + quad * 4 + r;
      Lv[split * N_NODES + row] = l0[r];
      Lv[split * N_NODES + row + 16] = l1[r];
    }
  }
}

// ---------------- combine splits (shared m) + Xnode + ReLU ----------------
__global__ __launch_bounds__(256) void k_comb(const u16* __restrict__ Op,
                                              const float* __restrict__ Lv,
                                              const float* __restrict__ Xnode,
                                              float* __restrict__ out) {
  int idx = blockIdx.x * 256 + threadIdx.x;
  int n = idx >> 6, c4 = (idx & 63) * 4;
  float L = 0.f;
  f32x4 acc = {0.f, 0.f, 0.f, 0.f};
#pragma unroll
  for (int s = 0; s < NSPLIT; s++) {
    L += Lv[s * N_NODES + n];
    u16x4 ov = *(const u16x4*)(Op + (size_t)s * N_NODES * 256 + (size_t)n * 256 + c4);
    acc.x += b2f(ov.x);
    acc.y += b2f(ov.y);
    acc.z += b2f(ov.z);
    acc.w += b2f(ov.w);
  }
  float invL = 1.0f / L;
  f32x4 xn = *(const f32x4*)(Xnode + (size_t)n * 256 + c4);
  f32x4 res;
  res.x = fmaxf(acc.x * invL + xn.x, 0.f);
  res.y = fmaxf(acc.y * invL + xn.y, 0.f);
  res.z = fmaxf(acc.z * invL + xn.z, 0.f);
  res.w = fmaxf(acc.w * invL + xn.w, 0.f);
  *(f32x4*)(out + (size_t)n * 256 + c4) = res;
}

extern "C" void kernel_launch(void* const* d_in, const int* in_sizes, int n_in,
                              void* d_out, int out_size, void* d_ws, size_t ws_size,
                              hipStream_t stream) {
  const float* X = (const float*)d_in[0];
  const int* v_ids = (const int*)d_in[1];
  const int* e_ids = (const int*)d_in[2];
  const float* Wq = (const float*)d_in[3];
  const float* bq = (const float*)d_in[4];
  const float* Wk = (const float*)d_in[5];
  const float* bk = (const float*)d_in[6];
  const float* Wv = (const float*)d_in[7];
  const float* bv = (const float*)d_in[8];
  const float* Wke = (const float*)d_in[9];
  const float* bke = (const float*)d_in[10];
  float* out = (float*)d_out;

  char* ws = (char*)d_ws;
  u16* Xb = (u16*)(ws);                       // 8 MB   [N][256] bf16
  u16* QKV = (u16*)(ws + 8388608);            // 24 MB  [N][768] bf16
  u16* Wt = (u16*)(ws + 33554432);            // 512 KB
  float* bcat = (float*)(ws + 34078720);      // 4 KB
  int* hist = (int*)(ws + 34082816);          // 32 KB
  int* eoff = (int*)(ws + 34115584);          // 36 KB
  int* cur = (int*)(ws + 34152448);           // 32 KB
  int* perm = (int*)(ws + 34185216);          // 1 MB
  u16* Xe = (u16*)(ws + 35233792);            // 4 MB
  u16* XeT = (u16*)(ws + 39428096);           // 4 MB
  u16* Keb = (u16*)(ws + 43622400);           // 4 MB
  float* Xnode = (float*)(ws + 47816704);     // 16 MB
  u16* Op = (u16*)(ws + 64593920);            // 32 MB  [4][N][256] bf16
  float* Lv = (float*)(ws + 98148352);        // 256 KB
  float* M2row = (float*)(ws + 98410496);     // 64 KB
  float* kappa = (float*)(ws + 98476032);     // 4 B

  hipMemsetAsync(hist, 0, 32768, stream);
  hipMemsetAsync(kappa, 0, 4, stream);
  k_cvt<<<4096, 256, 0, stream>>>(X, Xb);
  k_wt<<<dim3(256, 4), 256, 0, stream>>>(Wq, Wk, Wv, Wke, Wt);
  k_bias<<<4, 256, 0, stream>>>(bq, bk, bv, bke, bcat);
  k_hist<<<256, 256, 0, stream>>>(e_ids, hist);
  k_scan<<<1, 256, 0, stream>>>(hist, eoff, cur);
  k_perm<<<256, 256, 0, stream>>>(v_ids, e_ids, cur, perm);
  k_gather<<<8192, 256, 0, stream>>>(Xb, perm, eoff, Xe);
  k_xt<<<dim3(128, 4), 256, 0, stream>>>(Xe, XeT);
  k_gemm64<<<dim3(256, 12), 256, 0, stream>>>(Xb, Wt, bcat, QKV, 768);
  k_gemm64<<<dim3(128, 4), 256, 0, stream>>>(Xe, Wt + 3 * 65536, bcat + 768, Keb, 256);
  k_knorm<<<256, 256, 0, stream>>>(Keb, kappa);
  k_qnorm<<<4096, 256, 0, stream>>>(QKV, kappa, M2row);
  k_nodeattn<<<4096, 256, 0, stream>>>(QKV, Xnode);
  k_flash<<<512, 256, 0, stream>>>(QKV, Keb, XeT, M2row, Op, Lv);
  k_comb<<<4096, 256, 0, stream>>>(Op, Lv, Xnode, out);
}

// Round 6
// 405.768 us; speedup vs baseline: 2.4407x; 2.4407x over previous
//
#include <hip/hip_runtime.h>

typedef unsigned short u16;
typedef unsigned int u32;
typedef __attribute__((ext_vector_type(4))) float f32x4;
typedef __attribute__((ext_vector_type(8))) short bf16x8;
typedef __attribute__((ext_vector_type(4))) short bf16x4;
typedef __attribute__((ext_vector_type(4))) u16 u16x4;

#define N_NODES 16384
#define N_EDGES 8192
#define FK_SCALE 0.17677669529663687f
#define LOG2E 1.4426950408889634f
#define C1EXP (FK_SCALE * LOG2E)
#define NSPLIT 4

typedef const u32 __attribute__((address_space(1))) gu32;
typedef u32 __attribute__((address_space(3))) lu32;

__device__ __forceinline__ void gl_lds16(const void* g, void* l) {
  __builtin_amdgcn_global_load_lds((gu32*)g, (lu32*)l, 16, 0, 0);
}

__device__ __forceinline__ float b2f(u16 u) {
  return __builtin_bit_cast(float, (u32)u << 16);
}
__device__ __forceinline__ u16 f2b(float f) {
  u32 u = __builtin_bit_cast(u32, f);
  u += 0x7fffu + ((u >> 16) & 1u);
  return (u16)(u >> 16);
}

// ---------------- X -> bf16 ----------------
__global__ __launch_bounds__(256) void k_cvt(const float* __restrict__ X,
                                             u16* __restrict__ Xb) {
  int i = blockIdx.x * 256 + threadIdx.x;
  f32x4 v = *(const f32x4*)(X + i * 4);
  u16x4 r;
  r.x = f2b(v.x); r.y = f2b(v.y); r.z = f2b(v.z); r.w = f2b(v.w);
  *(u16x4*)(Xb + i * 4) = r;
}

// ---------------- W transpose+cvt ----------------
__global__ __launch_bounds__(256) void k_wt(const float* __restrict__ Wq,
                                            const float* __restrict__ Wk,
                                            const float* __restrict__ Wv,
                                            const float* __restrict__ Wke,
                                            u16* __restrict__ Wt) {
  int w = blockIdx.y;
  const float* W = (w == 0) ? Wq : (w == 1) ? Wk : (w == 2) ? Wv : Wke;
  int n = blockIdx.x;
  int k = threadIdx.x;
  Wt[w * 65536 + n * 256 + k] = f2b(W[k * 256 + n]);
}

// ---------------- bias pack ----------------
__global__ __launch_bounds__(256) void k_bias(const float* __restrict__ bq,
                                              const float* __restrict__ bk,
                                              const float* __restrict__ bv,
                                              const float* __restrict__ bke,
                                              float* __restrict__ bcat) {
  int i = blockIdx.x * 256 + threadIdx.x;
  float v;
  if (i < 256) v = bq[i];
  else if (i < 512) v = bk[i - 256];
  else if (i < 768) v = bv[i - 512];
  else v = bke[i - 768];
  bcat[i] = v;
}

// ---------------- histogram of e_ids ----------------
__global__ __launch_bounds__(256) void k_hist(const int* __restrict__ e_ids,
                                              int* __restrict__ hist) {
  int base = blockIdx.x * 1024 + threadIdx.x;
#pragma unroll
  for (int k = 0; k < 4; k++) atomicAdd(&hist[e_ids[base + k * 256]], 1);
}

// ---------------- exclusive scan (1 block) ----------------
__global__ __launch_bounds__(256) void k_scan(const int* __restrict__ hist,
                                              int* __restrict__ eoff,
                                              int* __restrict__ cur) {
  __shared__ int ts[256];
  int t = threadIdx.x;
  int base = t * 32;
  int vals[32];
  int s = 0;
#pragma unroll
  for (int i = 0; i < 32; i++) { vals[i] = hist[base + i]; s += vals[i]; }
  ts[t] = s;
  __syncthreads();
  for (int off = 1; off < 256; off <<= 1) {
    int v = (t >= off) ? ts[t - off] : 0;
    __syncthreads();
    ts[t] += v;
    __syncthreads();
  }
  int ex = ts[t] - s;
#pragma unroll
  for (int i = 0; i < 32; i++) {
    eoff[base + i] = ex;
    cur[base + i] = ex;
    ex += vals[i];
  }
  if (t == 255) eoff[8192] = ex;
}

// ---------------- permute ----------------
__global__ __launch_bounds__(256) void k_perm(const int* __restrict__ v_ids,
                                              const int* __restrict__ e_ids,
                                              int* __restrict__ cur,
                                              int* __restrict__ perm) {
  int base = blockIdx.x * 1024 + threadIdx.x;
#pragma unroll
  for (int k = 0; k < 4; k++) {
    int i = base + k * 256;
    int e = e_ids[i];
    int v = v_ids[i];
    int pos = atomicAdd(&cur[e], 1);
    perm[pos] = v;
  }
}

// ---------------- per-edge gather-mean ----------------
__global__ __launch_bounds__(256) void k_gather(const u16* __restrict__ Xb,
                                                const int* __restrict__ perm,
                                                const int* __restrict__ eoff,
                                                u16* __restrict__ Xe) {
  __shared__ float red[4][256];
  int e = blockIdx.x;
  int tid = threadIdx.x, wave = tid >> 6, lane = tid & 63;
  int start = eoff[e], end = eoff[e + 1];
  f32x4 acc = {0.f, 0.f, 0.f, 0.f};
  for (int j = start + wave; j < end; j += 4) {
    int v = perm[j];
    bf16x4 x = *(const bf16x4*)(Xb + v * 256 + lane * 4);
#pragma unroll
    for (int c = 0; c < 4; c++) acc[c] += b2f((u16)x[c]);
  }
  *(f32x4*)&red[wave][lane * 4] = acc;
  __syncthreads();
  int t = tid;
  float s = red[0][t] + red[1][t] + red[2][t] + red[3][t];
  float m = s / fmaxf((float)(end - start), 1.0f);
  Xe[e * 256 + t] = f2b(m);
}

// ---------------- transpose Xe -> XeT ----------------
__global__ __launch_bounds__(256) void k_xt(const u16* __restrict__ Xe,
                                            u16* __restrict__ XeT) {
  __shared__ u16 tile[64][65];
  int e0 = blockIdx.x * 64, c0 = blockIdx.y * 64;
  int tid = threadIdx.x;
#pragma unroll
  for (int i = 0; i < 16; i++) {
    int idx = i * 256 + tid;
    int er = idx >> 6, cr = idx & 63;
    tile[cr][er] = Xe[(e0 + er) * 256 + c0 + cr];
  }
  __syncthreads();
#pragma unroll
  for (int i = 0; i < 16; i++) {
    int idx = i * 256 + tid;
    int cr = idx >> 6, er = idx & 63;
    XeT[(c0 + cr) * 8192 + e0 + er] = tile[cr][er];
  }
}

// ---------------- GEMM 64x64, K=256 ----------------
__global__ __launch_bounds__(256) void k_gemm64(const u16* __restrict__ A,
                                                const u16* __restrict__ Wt,
                                                const float* __restrict__ bias,
                                                u16* __restrict__ out,
                                                int ldout) {
  __shared__ u16 As[64 * 256];
  __shared__ u16 Bs[64 * 256];
  int tid = threadIdx.x;
  int mtile = blockIdx.x * 64;
  int gn = blockIdx.y * 64;
  const u16* Ap = A + mtile * 256;
  const u16* Bp = Wt + gn * 256;
#pragma unroll
  for (int i = 0; i < 8; i++) {
    gl_lds16(Ap + i * 2048 + tid * 8, As + i * 2048 + tid * 8);
    gl_lds16(Bp + i * 2048 + tid * 8, Bs + i * 2048 + tid * 8);
  }
  __syncthreads();
  int wave = tid >> 6, lane = tid & 63;
  int quad = lane >> 4, l16 = lane & 15;
  bf16x8 a[8];
#pragma unroll
  for (int kc = 0; kc < 8; kc++)
    a[kc] = *(const bf16x8*)(As + (wave * 16 + l16) * 256 + kc * 32 + quad * 8);
#pragma unroll
  for (int nt = 0; nt < 4; nt++) {
    f32x4 acc = {0.f, 0.f, 0.f, 0.f};
#pragma unroll
    for (int kc = 0; kc < 8; kc++) {
      bf16x8 b = *(const bf16x8*)(Bs + (nt * 16 + l16) * 256 + kc * 32 + quad * 8);
      acc = __builtin_amdgcn_mfma_f32_16x16x32_bf16(a[kc], b, acc, 0, 0, 0);
    }
#pragma unroll
    for (int r = 0; r < 4; r++) {
      int row = mtile + wave * 16 + quad * 4 + r;
      int col = gn + nt * 16 + l16;
      out[row * ldout + col] = f2b(acc[r] + bias[col]);
    }
  }
}

// ---------------- kappa = max_e ||Ke_e||^2 (256 atomics total) ----------------
__global__ __launch_bounds__(256) void k_knorm(const u16* __restrict__ Keb,
                                               float* __restrict__ kappa) {
  __shared__ float red[4];
  int tid = threadIdx.x;
  int wave = tid >> 6, lane = tid & 63;
  float mx = 0.f;
#pragma unroll
  for (int i = 0; i < 8; i++) {
    int e = blockIdx.x * 32 + wave * 8 + i;
    bf16x4 x = *(const bf16x4*)(Keb + e * 256 + lane * 4);
    float s = 0.f;
#pragma unroll
    for (int c = 0; c < 4; c++) { float v = b2f((u16)x[c]); s += v * v; }
#pragma unroll
    for (int off = 1; off < 64; off <<= 1) s += __shfl_xor(s, off, 64);
    mx = fmaxf(mx, s);
  }
  if (lane == 0) red[wave] = mx;
  __syncthreads();
  if (tid == 0) {
    float m = fmaxf(fmaxf(red[0], red[1]), fmaxf(red[2], red[3]));
    atomicMax((int*)kappa, __float_as_int(m));  // all values >= 0
  }
}

// ---------------- M2row[n] = ||Qe_n|| * sqrt(kappa) * scale * log2e ----------------
__global__ __launch_bounds__(256) void k_qnorm(const u16* __restrict__ QKV,
                                               const float* __restrict__ kappa,
                                               float* __restrict__ M2row) {
  int tid = threadIdx.x;
  int wave = tid >> 6, lane = tid & 63;
  int n = blockIdx.x * 4 + wave;
  bf16x4 x = *(const bf16x4*)(QKV + n * 768 + lane * 4);
  float s = 0.f;
#pragma unroll
  for (int c = 0; c < 4; c++) { float v = b2f((u16)x[c]); s += v * v; }
#pragma unroll
  for (int off = 1; off < 64; off <<= 1) s += __shfl_xor(s, off, 64);
  if (lane == 0) M2row[n] = sqrtf(s * kappa[0]) * C1EXP;
}

// ---------------- per-node 8x8 head attention ----------------
__global__ __launch_bounds__(256) void k_nodeattn(const u16* __restrict__ QKV,
                                                  float* __restrict__ Xnode) {
  int tid = threadIdx.x;
  int wave = tid >> 6, lane = tid & 63;
  int n = blockIdx.x * 4 + wave;
  int h = lane >> 3, g = lane & 7;
  const u16* base = QKV + n * 768;
  const bf16x8* qp = (const bf16x8*)(base + h * 32);
  const bf16x8* kp = (const bf16x8*)(base + 256 + g * 32);
  float s = 0.f;
#pragma unroll
  for (int t = 0; t < 4; t++) {
    bf16x8 qv = qp[t], kv = kp[t];
#pragma unroll
    for (int j = 0; j < 8; j++) s += b2f((u16)qv[j]) * b2f((u16)kv[j]);
  }
  s *= FK_SCALE;
  float mx = s;
#pragma unroll
  for (int off = 1; off < 8; off <<= 1) mx = fmaxf(mx, __shfl_xor(mx, off, 64));
  float p = __builtin_amdgcn_exp2f((s - mx) * LOG2E);
  float l = p;
#pragma unroll
  for (int off = 1; off < 8; off <<= 1) l += __shfl_xor(l, off, 64);
  float attn = p / l;
  float a4[4] = {0.f, 0.f, 0.f, 0.f};
#pragma unroll
  for (int g2 = 0; g2 < 8; g2++) {
    float a = __shfl(attn, (lane & 56) | g2, 64);
    bf16x4 vv = *(const bf16x4*)(base + 512 + g2 * 32 + g * 4);
#pragma unroll
    for (int j = 0; j < 4; j++) a4[j] += a * b2f((u16)vv[j]);
  }
  f32x4 o = {a4[0], a4[1], a4[2], a4[3]};
  *(f32x4*)(Xnode + n * 256 + h * 32 + g * 4) = o;
}

// ---------------- flash partial, fixed-m, Bq=16/wave, 2 blocks/CU ----------------
// 1024 blocks = 256 q-tiles x 4 splits; 4 waves; Bq=64/block (16/wave); Bk=64.
// LDS 72 KB: KeL 32K swz | VL 32K swz | PL 8K (4 x [16][64] swz).
// __launch_bounds__(256,2): total regs <= 256 (acc 64 + qf 32 + ~100 scratch),
// 2 blocks/CU -> one block's barrier drain overlaps the other's MFMA.
__global__ __launch_bounds__(256, 2) void k_flash(const u16* __restrict__ QKV,
                                                  const u16* __restrict__ Keb,
                                                  const u16* __restrict__ XeT,
                                                  const float* __restrict__ M2row,
                                                  u16* __restrict__ Op,
                                                  float* __restrict__ Lv) {
  extern __shared__ u16 sm[];
  u16* KeL = sm;               // [64][256] swizzled
  u16* VL = sm + 16384;        // [256][64] swizzled
  u16* PL = sm + 32768;        // [4][16][64] swizzled
  int tid = threadIdx.x;
  int wave = tid >> 6, lane = tid & 63;
  int quad = lane >> 4, l16 = lane & 15;
  int qt = blockIdx.x & 255;
  int split = blockIdx.x >> 8;
  int row0 = qt * 64 + wave * 16;
  u16* PLw = PL + (wave << 10);

  // Q fragments (1 m-tile / wave)
  bf16x8 qf[8];
#pragma unroll
  for (int kc = 0; kc < 8; kc++)
    qf[kc] = *(const bf16x8*)(QKV + (row0 + l16) * 768 + kc * 32 + quad * 8);

  float mb[4];
#pragma unroll
  for (int r = 0; r < 4; r++) mb[r] = M2row[row0 + quad * 4 + r];

  f32x4 o[16];
#pragma unroll
  for (int i = 0; i < 16; i++) o[i] = (f32x4){0.f, 0.f, 0.f, 0.f};
  float l[4] = {0.f, 0.f, 0.f, 0.f};

  for (int ktl = 0; ktl < 32; ktl++) {
    int ktg = split * 32 + ktl;
    __syncthreads();  // prev tile fully consumed
    {
      const u16* kp = Keb + ktg * 16384;
#pragma unroll
      for (int i = 0; i < 8; i++) {
        int s = i * 256 + tid;
        int r = s >> 5, p = s & 31;
        int c = (p & 24) | ((p & 7) ^ (r & 7));
        gl_lds16(kp + r * 256 + c * 8, KeL + s * 8);
      }
#pragma unroll
      for (int i = 0; i < 8; i++) {
        int s = i * 256 + tid;
        int c = s >> 3, p = s & 7;
        int k8 = p ^ (c & 7);
        gl_lds16(XeT + c * 8192 + ktg * 64 + k8 * 8, VL + s * 8);
      }
    }
    __syncthreads();  // tiles resident

    // QK^T per nt, immediate exp (fixed-m), P -> per-wave LDS
#pragma unroll
    for (int nt = 0; nt < 4; nt++) {
      f32x4 a = {0.f, 0.f, 0.f, 0.f};
#pragma unroll
      for (int kc = 0; kc < 8; kc++) {
        int r = nt * 16 + l16;
        int c = kc * 4 + quad;
        int p = (c & 24) | ((c & 7) ^ (r & 7));
        bf16x8 kb = *(const bf16x8*)(KeL + r * 256 + p * 8);
        a = __builtin_amdgcn_mfma_f32_16x16x32_bf16(qf[kc], kb, a, 0, 0, 0);
      }
      int col = nt * 16 + l16;
#pragma unroll
      for (int r = 0; r < 4; r++) {
        float pv = __builtin_amdgcn_exp2f(a[r] * C1EXP - mb[r]);
        l[r] += pv;
        int row = quad * 4 + r;
        PLw[row * 64 + (((col >> 3) ^ (row & 7)) << 3) + (col & 7)] = f2b(pv);
      }
    }
    // P A-fragments (same-wave LDS round trip, no barrier)
    bf16x8 pf[2];
#pragma unroll
    for (int kc2 = 0; kc2 < 2; kc2++) {
      int ck = kc2 * 4 + quad;
      pf[kc2] = *(const bf16x8*)(PLw + l16 * 64 + ((ck ^ (l16 & 7)) << 3));
    }
    // PV
#pragma unroll
    for (int ct = 0; ct < 16; ct++) {
#pragma unroll
      for (int kc2 = 0; kc2 < 2; kc2++) {
        int rv = ct * 16 + l16;
        int ck = kc2 * 4 + quad;
        bf16x8 vb = *(const bf16x8*)(VL + rv * 64 + ((ck ^ (rv & 7)) << 3));
        o[ct] = __builtin_amdgcn_mfma_f32_16x16x32_bf16(pf[kc2], vb, o[ct], 0, 0, 0);
      }
    }
  }

  // reduce row-sums across the 16 lanes of each row
#pragma unroll
  for (int off = 1; off < 16; off <<= 1)
#pragma unroll
    for (int r = 0; r < 4; r++) l[r] += __shfl_xor(l[r], off, 64);

  size_t obase = (size_t)split * N_NODES * 256;
#pragma unroll
  for (int ct = 0; ct < 16; ct++)
#pragma unroll
    for (int r = 0; r < 4; r++) {
      int row = row0 + quad * 4 + r;
      int col = ct * 16 + l16;
      Op[obase + (size_t)row * 256 + col] = f2b(o[ct][r]);
    }
  if (l16 == 0) {
#pragma unroll
    for (int r = 0; r < 4; r++)
      Lv[split * N_NODES + row0 + quad * 4 + r] = l[r];
  }
}

// ---------------- combine splits (shared m) + Xnode + ReLU ----------------
__global__ __launch_bounds__(256) void k_comb(const u16* __restrict__ Op,
                                              const float* __restrict__ Lv,
                                              const float* __restrict__ Xnode,
                                              float* __restrict__ out) {
  int idx = blockIdx.x * 256 + threadIdx.x;
  int n = idx >> 6, c4 = (idx & 63) * 4;
  float L = 0.f;
  f32x4 acc = {0.f, 0.f, 0.f, 0.f};
#pragma unroll
  for (int s = 0; s < NSPLIT; s++) {
    L += Lv[s * N_NODES + n];
    u16x4 ov = *(const u16x4*)(Op + (size_t)s * N_NODES * 256 + (size_t)n * 256 + c4);
    acc.x += b2f(ov.x);
    acc.y += b2f(ov.y);
    acc.z += b2f(ov.z);
    acc.w += b2f(ov.w);
  }
  float invL = 1.0f / L;
  f32x4 xn = *(const f32x4*)(Xnode + (size_t)n * 256 + c4);
  f32x4 res;
  res.x = fmaxf(acc.x * invL + xn.x, 0.f);
  res.y = fmaxf(acc.y * invL + xn.y, 0.f);
  res.z = fmaxf(acc.z * invL + xn.z, 0.f);
  res.w = fmaxf(acc.w * invL + xn.w, 0.f);
  *(f32x4*)(out + (size_t)n * 256 + c4) = res;
}

extern "C" void kernel_launch(void* const* d_in, const int* in_sizes, int n_in,
                              void* d_out, int out_size, void* d_ws, size_t ws_size,
                              hipStream_t stream) {
  const float* X = (const float*)d_in[0];
  const int* v_ids = (const int*)d_in[1];
  const int* e_ids = (const int*)d_in[2];
  const float* Wq = (const float*)d_in[3];
  const float* bq = (const float*)d_in[4];
  const float* Wk = (const float*)d_in[5];
  const float* bk = (const float*)d_in[6];
  const float* Wv = (const float*)d_in[7];
  const float* bv = (const float*)d_in[8];
  const float* Wke = (const float*)d_in[9];
  const float* bke = (const float*)d_in[10];
  float* out = (float*)d_out;

  char* ws = (char*)d_ws;
  u16* Xb = (u16*)(ws);                       // 8 MB   [N][256] bf16
  u16* QKV = (u16*)(ws + 8388608);            // 24 MB  [N][768] bf16
  u16* Wt = (u16*)(ws + 33554432);            // 512 KB
  float* bcat = (float*)(ws + 34078720);      // 4 KB
  int* hist = (int*)(ws + 34082816);          // 32 KB
  int* eoff = (int*)(ws + 34115584);          // 36 KB
  int* cur = (int*)(ws + 34152448);           // 32 KB
  int* perm = (int*)(ws + 34185216);          // 1 MB
  u16* Xe = (u16*)(ws + 35233792);            // 4 MB
  u16* XeT = (u16*)(ws + 39428096);           // 4 MB
  u16* Keb = (u16*)(ws + 43622400);           // 4 MB
  float* Xnode = (float*)(ws + 47816704);     // 16 MB
  u16* Op = (u16*)(ws + 64593920);            // 32 MB  [4][N][256] bf16
  float* Lv = (float*)(ws + 98148352);        // 256 KB
  float* M2row = (float*)(ws + 98410496);     // 64 KB
  float* kappa = (float*)(ws + 98476032);     // 4 B

  hipMemsetAsync(hist, 0, 32768, stream);
  hipMemsetAsync(kappa, 0, 4, stream);
  k_cvt<<<4096, 256, 0, stream>>>(X, Xb);
  k_wt<<<dim3(256, 4), 256, 0, stream>>>(Wq, Wk, Wv, Wke, Wt);
  k_bias<<<4, 256, 0, stream>>>(bq, bk, bv, bke, bcat);
  k_hist<<<256, 256, 0, stream>>>(e_ids, hist);
  k_scan<<<1, 256, 0, stream>>>(hist, eoff, cur);
  k_perm<<<256, 256, 0, stream>>>(v_ids, e_ids, cur, perm);
  k_gather<<<8192, 256, 0, stream>>>(Xb, perm, eoff, Xe);
  k_xt<<<dim3(128, 4), 256, 0, stream>>>(Xe, XeT);
  k_gemm64<<<dim3(256, 12), 256, 0, stream>>>(Xb, Wt, bcat, QKV, 768);
  k_gemm64<<<dim3(128, 4), 256, 0, stream>>>(Xe, Wt + 3 * 65536, bcat + 768, Keb, 256);
  k_knorm<<<256, 256, 0, stream>>>(Keb, kappa);
  k_qnorm<<<4096, 256, 0, stream>>>(QKV, kappa, M2row);
  k_nodeattn<<<4096, 256, 0, stream>>>(QKV, Xnode);
  hipFuncSetAttribute((const void*)k_flash, hipFuncAttributeMaxDynamicSharedMemorySize,
                      73728);
  k_flash<<<1024, 256, 73728, stream>>>(QKV, Keb, XeT, M2row, Op, Lv);
  k_comb<<<4096, 256, 0, stream>>>(Op, Lv, Xnode, out);
}